// Round 8
// baseline (678.340 us; speedup 1.0000x reference)
//
#include <hip/hip_runtime.h>
#include <hip/hip_bf16.h>
#include <math.h>

typedef unsigned short u16;
typedef __attribute__((ext_vector_type(8))) short short8;
typedef __attribute__((ext_vector_type(4))) float floatx4;

#define DEVINL __device__ __forceinline__
#define AS1 __attribute__((address_space(1)))
#define AS3 __attribute__((address_space(3)))

DEVINL float bf2f(u16 u) { union { unsigned int i; float f; } v; v.i = ((unsigned int)u) << 16; return v.f; }
DEVINL u16 f2bf(float f) {
  union { unsigned int i; float f; } v; v.f = f;
  unsigned int i = v.i;
  unsigned int r = (i + 0x7fffu + ((i >> 16) & 1u)) >> 16;
  return (u16)r;
}

// ---------------------------------------------------------------------------
// k_prep: all weight conversions in ONE dispatch. grid (768, 5).
// ---------------------------------------------------------------------------
__global__ __launch_bounds__(256) void k_prep(
    const float* __restrict__ cf_w1, u16* __restrict__ wc1,
    const float* __restrict__ sc_w1, u16* __restrict__ ws1,
    const float* __restrict__ cf_w2, u16* __restrict__ wc2,
    const float* __restrict__ sc_w2, u16* __restrict__ ws2p,
    const float* __restrict__ sc_b2, float* __restrict__ scb2p) {
  int i = blockIdx.x * 256 + threadIdx.x;
  int job = blockIdx.y;
  if (job == 4) {
    if (i < 128) scb2p[i] = (i < 64) ? sc_b2[i] : 0.f;
    return;
  }
  const float* src = (job == 0) ? cf_w1 : (job == 1) ? sc_w1 : (job == 2) ? cf_w2 : sc_w2;
  u16* dst = (job == 0) ? wc1 : (job == 1) ? ws1 : (job == 2) ? wc2 : ws2p;
  int n4 = (job <= 1) ? 196608 : 16384;
  if (i >= n4) return;
  ushort4 o = {0, 0, 0, 0};
  if (job != 3 || (i >> 7) < 64) {
    float4 v = ((const float4*)src)[i];
    o.x = f2bf(v.x); o.y = f2bf(v.y); o.z = f2bf(v.z); o.w = f2bf(v.w);
  }
  ((ushort4*)dst)[i] = o;
}

// ---------------------------------------------------------------------------
// K0: transpose+convert x[b][c][n] (f32) -> xT[b][n][c] (bf16), 64x64 tiles
// ---------------------------------------------------------------------------
__global__ __launch_bounds__(256) void k_transpose(const float* __restrict__ x,
                                                   u16* __restrict__ xT,
                                                   int nC, int nN) {
  __shared__ u16 tile[64 * 65];
  int b = blockIdx.z;
  int c0 = blockIdx.y * 64, n0 = blockIdx.x * 64;
  const float* xb = x + ((long)b * nC + c0) * nN + n0;
  u16* xTb = xT + ((long)b * nN + n0) * nC + c0;
  int tid = threadIdx.x;
#pragma unroll
  for (int p = 0; p < 2; ++p) {
    int u = tid + p * 256;
    int r = u >> 3, nc = (u & 7) * 8;
    const float4* srcp = (const float4*)(xb + (long)r * nN + nc);
    float4 v0 = srcp[0], v1 = srcp[1];
    int base = r * 65 + nc;
    tile[base + 0] = f2bf(v0.x); tile[base + 1] = f2bf(v0.y);
    tile[base + 2] = f2bf(v0.z); tile[base + 3] = f2bf(v0.w);
    tile[base + 4] = f2bf(v1.x); tile[base + 5] = f2bf(v1.y);
    tile[base + 6] = f2bf(v1.z); tile[base + 7] = f2bf(v1.w);
  }
  __syncthreads();
#pragma unroll
  for (int p = 0; p < 2; ++p) {
    int u = tid + p * 256;
    int nr = u >> 3, cc = (u & 7) * 8;
    __align__(16) u16 tmp[8];
#pragma unroll
    for (int j = 0; j < 8; ++j) tmp[j] = tile[(cc + j) * 65 + nr];
    *(uint4*)(xTb + (long)nr * nC + cc) = *(uint4*)(tmp);
  }
}

// ---------------------------------------------------------------------------
// gemm64: Out[M,N] = A[M,K] * B[Ncols,K]^T (+bias, relu), bf16 in, fp32 acc.
// FULL TILES. BK=64, width-16 global_load_lds, XOR k-piece swizzle (conflict-
// free, R6-verified), XCD swizzle (m = blockIdx.x, R7-verified FETCH 4x drop).
// NEW: wave-uniform base pointer advance (+128 B/iter, SALU) + loop-invariant
// per-lane byte offsets -> no per-iter VALU address math.
// ---------------------------------------------------------------------------
template <int KT, bool OUT_F32, int BIAS_MODE, bool RELU>
__global__ __launch_bounds__(256) void k_gemm64(
    const u16* __restrict__ A, int lda, long aBS,
    const u16* __restrict__ B1, const u16* __restrict__ B2, int nSplit,
    int ldb, long bBS,
    void* __restrict__ Out, int ldo, long oBS,
    const float* __restrict__ bias1, const float* __restrict__ bias2) {
  __shared__ __align__(16) u16 As[128 * 64];
  __shared__ __align__(16) u16 Bs[128 * 64];
  int bz = blockIdx.z;
  int m0 = blockIdx.x * 128, n0 = blockIdx.y * 128;
  const char* pA = (const char*)(A + (long)bz * aBS + (long)m0 * lda);
  const char* pB = (const char*)(
      ((n0 < nSplit) ? (B1 + (long)n0 * ldb) : (B2 + (long)(n0 - nSplit) * ldb)) +
      (long)bz * bBS);
  int tid = threadIdx.x;
  int lane = tid & 63;
  int lane16 = lane & 15, quad = lane >> 4;
  int wid = tid >> 6;
  int wm = wid >> 1, wn = wid & 1;

  int rIn = lane >> 3;
  int kkSw = ((lane & 7) ^ rIn) * 8;

  // loop-invariant per-lane byte offsets; uniform base advances per iter
  int voA[4], voB[4];
#pragma unroll
  for (int h = 0; h < 4; ++h) {
    int r = (wid * 4 + h) * 8 + rIn;
    voA[h] = (r * lda + kkSw) * 2;
    voB[h] = (r * ldb + kkSw) * 2;
  }

  floatx4 acc[4][4];
#pragma unroll
  for (int i = 0; i < 4; ++i)
#pragma unroll
    for (int j = 0; j < 4; ++j) acc[i][j] = (floatx4){0.f, 0.f, 0.f, 0.f};

  for (int kt = 0; kt < KT; ++kt) {
    __syncthreads();
#pragma unroll
    for (int h = 0; h < 4; ++h) {
      __builtin_amdgcn_global_load_lds((const AS1 void*)(pA + voA[h]),
                                       (AS3 void*)&As[(wid * 4 + h) * 512], 16, 0, 0);
      __builtin_amdgcn_global_load_lds((const AS1 void*)(pB + voB[h]),
                                       (AS3 void*)&Bs[(wid * 4 + h) * 512], 16, 0, 0);
    }
    pA += 128;  // 64 bf16 per K-step
    pB += 128;
    __syncthreads();
#pragma unroll
    for (int h2 = 0; h2 < 2; ++h2) {
      short8 af[4], bfr[4];
#pragma unroll
      for (int t = 0; t < 4; ++t) {
        int ra = wm * 64 + t * 16 + lane16;
        af[t] = *(const short8*)&As[ra * 64 + (((h2 * 4 + quad) ^ (ra & 7)) * 8)];
      }
#pragma unroll
      for (int t = 0; t < 4; ++t) {
        int rb = wn * 64 + t * 16 + lane16;
        bfr[t] = *(const short8*)&Bs[rb * 64 + (((h2 * 4 + quad) ^ (rb & 7)) * 8)];
      }
#pragma unroll
      for (int i = 0; i < 4; ++i)
#pragma unroll
        for (int j = 0; j < 4; ++j)
          acc[i][j] = __builtin_amdgcn_mfma_f32_16x16x32_bf16(af[i], bfr[j],
                                                              acc[i][j], 0, 0, 0);
    }
  }

  // epilogue: C/D layout col=lane&15, row=quad*4+reg  [m89-verified]
  const float* bcolPtr = bias1;
  int bofs = 0;
  if (BIAS_MODE == 2 && n0 >= nSplit) { bcolPtr = bias2; bofs = nSplit; }
#pragma unroll
  for (int i = 0; i < 4; ++i) {
    int rowb = m0 + wm * 64 + i * 16 + quad * 4;
#pragma unroll
    for (int j = 0; j < 4; ++j) {
      int col = n0 + wn * 64 + j * 16 + lane16;
      float bc = 0.f;
      if (BIAS_MODE == 2) bc = bcolPtr[col - bofs];
#pragma unroll
      for (int r = 0; r < 4; ++r) {
        int row = rowb + r;
        float v = acc[i][j][r];
        if (BIAS_MODE == 2) v += bc;
        if (BIAS_MODE == 1) v += bias1[row];
        if (RELU) v = fmaxf(v, 0.f);
        if (OUT_F32)
          ((float*)Out)[(long)bz * oBS + (long)row * ldo + col] = v;
        else
          ((u16*)Out)[(long)bz * oBS + (long)row * ldo + col] = f2bf(v);
      }
    }
  }
}

// ---------------------------------------------------------------------------
// K2 fused: grid (8, 2, c). y=0: f = wc2.hT_cf^T + cf_b2; y=1: scores.
// M=128, N=1024, K=512 (KT=8). Same addressing scheme.
// ---------------------------------------------------------------------------
__global__ __launch_bounds__(256) void k_k2dual(
    const u16* __restrict__ wA, const u16* __restrict__ wB,
    const u16* __restrict__ hT, u16* __restrict__ fOut, u16* __restrict__ sOut,
    const float* __restrict__ bA, const float* __restrict__ bB) {
  __shared__ __align__(16) u16 As[128 * 64];
  __shared__ __align__(16) u16 Bs[128 * 64];
  int sel = blockIdx.y, bz = blockIdx.z;
  int n0 = blockIdx.x * 128;
  const char* pA = (const char*)(sel ? wB : wA);
  const char* pB = (const char*)(hT + (long)bz * 1048576 + (sel ? 512 : 0) +
                                 (long)n0 * 1024);
  u16* Out = (sel ? sOut : fOut) + (long)bz * 131072;
  const float* bias = sel ? bB : bA;
  int tid = threadIdx.x;
  int lane = tid & 63;
  int lane16 = lane & 15, quad = lane >> 4;
  int wid = tid >> 6;
  int wm = wid >> 1, wn = wid & 1;
  int rIn = lane >> 3;
  int kkSw = ((lane & 7) ^ rIn) * 8;

  int voA[4], voB[4];
#pragma unroll
  for (int h = 0; h < 4; ++h) {
    int r = (wid * 4 + h) * 8 + rIn;
    voA[h] = (r * 512 + kkSw) * 2;
    voB[h] = (r * 1024 + kkSw) * 2;
  }

  floatx4 acc[4][4];
#pragma unroll
  for (int i = 0; i < 4; ++i)
#pragma unroll
    for (int j = 0; j < 4; ++j) acc[i][j] = (floatx4){0.f, 0.f, 0.f, 0.f};

  for (int kt = 0; kt < 8; ++kt) {
    __syncthreads();
#pragma unroll
    for (int h = 0; h < 4; ++h) {
      __builtin_amdgcn_global_load_lds((const AS1 void*)(pA + voA[h]),
                                       (AS3 void*)&As[(wid * 4 + h) * 512], 16, 0, 0);
      __builtin_amdgcn_global_load_lds((const AS1 void*)(pB + voB[h]),
                                       (AS3 void*)&Bs[(wid * 4 + h) * 512], 16, 0, 0);
    }
    pA += 128;
    pB += 128;
    __syncthreads();
#pragma unroll
    for (int h2 = 0; h2 < 2; ++h2) {
      short8 af[4], bfr[4];
#pragma unroll
      for (int t = 0; t < 4; ++t) {
        int ra = wm * 64 + t * 16 + lane16;
        af[t] = *(const short8*)&As[ra * 64 + (((h2 * 4 + quad) ^ (ra & 7)) * 8)];
      }
#pragma unroll
      for (int t = 0; t < 4; ++t) {
        int rb = wn * 64 + t * 16 + lane16;
        bfr[t] = *(const short8*)&Bs[rb * 64 + (((h2 * 4 + quad) ^ (rb & 7)) * 8)];
      }
#pragma unroll
      for (int i = 0; i < 4; ++i)
#pragma unroll
        for (int j = 0; j < 4; ++j)
          acc[i][j] = __builtin_amdgcn_mfma_f32_16x16x32_bf16(af[i], bfr[j],
                                                              acc[i][j], 0, 0, 0);
    }
  }
#pragma unroll
  for (int i = 0; i < 4; ++i) {
    int rowb = wm * 64 + i * 16 + quad * 4;
#pragma unroll
    for (int j = 0; j < 4; ++j) {
      int col = n0 + wn * 64 + j * 16 + lane16;
#pragma unroll
      for (int r = 0; r < 4; ++r) {
        int row = rowb + r;
        Out[(long)row * 1024 + col] = f2bf(acc[i][j][r] + bias[row]);
      }
    }
  }
}

// ---------------------------------------------------------------------------
// K3: Sinkhorn, one 1024-thread block per batch. S column cached in 64 VGPRs
// per thread (all s[] loops fully unrolled -> stays in registers).
// u-pass: per-row LSE across 1024 threads via wave-reduce + LDS combine.
// v-pass: pure-register per-thread LSE over 65 rows.
// ---------------------------------------------------------------------------
DEVINL float waveMax(float x) {
#pragma unroll
  for (int off = 32; off > 0; off >>= 1) x = fmaxf(x, __shfl_xor(x, off));
  return x;
}
DEVINL float waveSum(float x) {
#pragma unroll
  for (int off = 32; off > 0; off >>= 1) x += __shfl_xor(x, off);
  return x;
}

__global__ __launch_bounds__(1024) void k_sinkhorn(
    const u16* __restrict__ S, const float* __restrict__ alphaPtr,
    float lmu, float lmu_bin, float lnu, float norm, u16* __restrict__ P) {
  __shared__ float wred[65][17];
  __shared__ float rowm[65];
  __shared__ float u_[65];
  int b = blockIdx.x, tid = threadIdx.x;
  int wid = tid >> 6, lane = tid & 63;
  const u16* Sb = S + (long)b * 131072;
  float alpha = *alphaPtr;
  float s[64];
#pragma unroll
  for (int i = 0; i < 64; ++i) s[i] = bf2f(Sb[i * 1024 + tid]);
  float v = 0.f;
  for (int it = 0; it < 3; ++it) {
    // u-pass: row max across all 1024 threads
#pragma unroll
    for (int i = 0; i < 65; ++i) {
      float z = (i < 64 ? s[i] : alpha) + v;
      float m = waveMax(z);
      if (lane == 0) wred[i][wid] = m;
    }
    __syncthreads();
    if (tid < 65) {
      float m = wred[tid][0];
#pragma unroll
      for (int w = 1; w < 16; ++w) m = fmaxf(m, wred[tid][w]);
      rowm[tid] = m;
    }
    __syncthreads();
    // u-pass: row sum of exp
#pragma unroll
    for (int i = 0; i < 65; ++i) {
      float z = (i < 64 ? s[i] : alpha) + v;
      float e = __expf(z - rowm[i]);
      float sm = waveSum(e);
      if (lane == 0) wred[i][wid] = sm;
    }
    __syncthreads();
    if (tid < 65) {
      float sm = 0.f;
#pragma unroll
      for (int w = 0; w < 16; ++w) sm += wred[tid][w];
      u_[tid] = (tid < 64 ? lmu : lmu_bin) - (rowm[tid] + __logf(sm));
    }
    __syncthreads();
    // v-pass: per-thread column LSE over 65 rows (registers only)
    float mx = alpha + u_[64];
#pragma unroll
    for (int i = 0; i < 64; ++i) mx = fmaxf(mx, s[i] + u_[i]);
    float sum = __expf(alpha + u_[64] - mx);
#pragma unroll
    for (int i = 0; i < 64; ++i) sum += __expf(s[i] + u_[i] - mx);
    v = lnu - (mx + __logf(sum));
    __syncthreads();
  }
  u16* Pb = P + (long)b * 65536;
#pragma unroll
  for (int i = 0; i < 64; ++i) {
    float z = s[i] + u_[i] + v - norm;
    Pb[i * 1024 + tid] = f2bf(__expf(fminf(z, 1.0f)));  // z<=0 mathematically
  }
}

// ---------------------------------------------------------------------------
// K4: split-K agg partials. aggP[kc][b][128][64] = f[b,128,ks] P[b,64,ks]^T
// ---------------------------------------------------------------------------
__global__ __launch_bounds__(256) void k_agg(const u16* __restrict__ f,
                                             const u16* __restrict__ P,
                                             float* __restrict__ aggP) {
  __shared__ __align__(16) u16 Fs[128 * 32];
  __shared__ __align__(16) u16 Ps[64 * 32];
  int bz = blockIdx.z, kc = blockIdx.x;
  int tid = threadIdx.x, wid = tid >> 6, lane = tid & 63;
  int lane16 = lane & 15, quad = lane >> 4;
  int rA0 = lane >> 2, kk = (lane & 3) * 8;
  const char* pF = (const char*)(f + (long)bz * 131072 + kc * 256);
  const char* pP = (const char*)(P + (long)bz * 65536 + kc * 256);
  int voF[2];
#pragma unroll
  for (int h = 0; h < 2; ++h)
    voF[h] = (((wid * 2 + h) * 16 + rA0) * 1024 + kk) * 2;
  int voP = ((wid * 16 + rA0) * 1024 + kk) * 2;

  floatx4 acc[2][4];
#pragma unroll
  for (int i = 0; i < 2; ++i)
#pragma unroll
    for (int j = 0; j < 4; ++j) acc[i][j] = (floatx4){0.f, 0.f, 0.f, 0.f};

  for (int kt = 0; kt < 8; ++kt) {
    __syncthreads();
#pragma unroll
    for (int h = 0; h < 2; ++h)
      __builtin_amdgcn_global_load_lds((const AS1 void*)(pF + voF[h]),
                                       (AS3 void*)&Fs[(wid * 2 + h) * 512], 16, 0, 0);
    __builtin_amdgcn_global_load_lds((const AS1 void*)(pP + voP),
                                     (AS3 void*)&Ps[wid * 512], 16, 0, 0);
    pF += 64;  // 32 bf16 per K-step
    pP += 64;
    __syncthreads();
    short8 af[2], bfr[4];
#pragma unroll
    for (int t = 0; t < 2; ++t)
      af[t] = *(const short8*)&Fs[(wid * 32 + t * 16 + lane16) * 32 + quad * 8];
#pragma unroll
    for (int j = 0; j < 4; ++j)
      bfr[j] = *(const short8*)&Ps[(j * 16 + lane16) * 32 + quad * 8];
#pragma unroll
    for (int i = 0; i < 2; ++i)
#pragma unroll
      for (int j = 0; j < 4; ++j)
        acc[i][j] = __builtin_amdgcn_mfma_f32_16x16x32_bf16(af[i], bfr[j],
                                                            acc[i][j], 0, 0, 0);
  }
  float* ab = aggP + ((long)kc * 32 + bz) * 8192;
#pragma unroll
  for (int i = 0; i < 2; ++i)
#pragma unroll
    for (int j = 0; j < 4; ++j)
#pragma unroll
      for (int r = 0; r < 4; ++r) {
        int row = wid * 32 + i * 16 + quad * 4 + r;
        int col = j * 16 + lane16;
        ab[row * 64 + col] = acc[i][j][r];
      }
}

// ---------------------------------------------------------------------------
// token MLP, parallelized.
// ---------------------------------------------------------------------------
__global__ __launch_bounds__(256) void k_mlp1(const float* __restrict__ t,
                                              const float* __restrict__ w1,
                                              const float* __restrict__ b1,
                                              float* __restrict__ h1) {
  __shared__ float tl[1536];
  int b = blockIdx.y, og = blockIdx.x;
  int tid = threadIdx.x, wid = tid >> 6, lane = tid & 63;
  for (int i = tid; i < 1536; i += 256) tl[i] = t[b * 1536 + i];
  __syncthreads();
#pragma unroll 4
  for (int oi = 0; oi < 16; ++oi) {
    int o = og * 64 + wid * 16 + oi;
    const float* wr = w1 + (long)o * 1536;
    float acc = 0.f;
#pragma unroll
    for (int s = 0; s < 24; ++s) { int c = lane + s * 64; acc += tl[c] * wr[c]; }
    acc = waveSum(acc);
    if (lane == 0) h1[b * 512 + o] = fmaxf(acc + b1[o], 0.f);
  }
}

__global__ __launch_bounds__(256) void k_mlp2(const float* __restrict__ h1,
                                              const float* __restrict__ w2,
                                              const float* __restrict__ b2,
                                              float* __restrict__ tk) {
  __shared__ float hl[512];
  int b = blockIdx.y, og = blockIdx.x;
  int tid = threadIdx.x, wid = tid >> 6, lane = tid & 63;
  for (int i = tid; i < 512; i += 256) hl[i] = h1[b * 512 + i];
  __syncthreads();
#pragma unroll 4
  for (int oi = 0; oi < 16; ++oi) {
    int o = og * 64 + wid * 16 + oi;
    const float* wr = w2 + (long)o * 512;
    float acc = 0.f;
#pragma unroll
    for (int s = 0; s < 8; ++s) { int c = lane + s * 64; acc += hl[c] * wr[c]; }
    acc = waveSum(acc);
    if (lane == 0) tk[b * 256 + o] = acc + b2[o];
  }
}

// ---------------------------------------------------------------------------
// K5: norms + output.
// ---------------------------------------------------------------------------
DEVINL float blockSum256(float x, float* red) {
#pragma unroll
  for (int off = 32; off > 0; off >>= 1) x += __shfl_xor(x, off);
  int wid = threadIdx.x >> 6;
  __syncthreads();
  if ((threadIdx.x & 63) == 0) red[wid] = x;
  __syncthreads();
  return red[0] + red[1] + red[2] + red[3];
}

__global__ __launch_bounds__(256) void k_norms(const float* __restrict__ tk,
                                               const float* __restrict__ aggP,
                                               float* __restrict__ out) {
  __shared__ float asum[8192];
  __shared__ float cn[64];
  __shared__ float red[4];
  int b = blockIdx.x, tid = threadIdx.x;
  const float* a0 = aggP + (long)b * 8192;
  for (int idx = tid; idx < 8192; idx += 256)
    asum[idx] = a0[idx] + a0[32 * 8192 + idx] + a0[64 * 8192 + idx] +
                a0[96 * 8192 + idx];
  __syncthreads();
  float tkv = tk[b * 256 + tid];
  float tss = blockSum256(tkv * tkv, red);
  float tn = fmaxf(sqrtf(tss), 1e-12f);
  if (tid < 64) {
    float s = 0.f;
    for (int l = 0; l < 128; ++l) { float a = asum[l * 64 + tid]; s += a * a; }
    cn[tid] = fmaxf(sqrtf(s), 1e-12f);
  }
  __syncthreads();
  float gs = (tkv / tn) * (tkv / tn);
  for (int idx = tid; idx < 8192; idx += 256) {
    float a = asum[idx] / cn[idx & 63];
    gs += a * a;
  }
  float G = blockSum256(gs, red);
  float inv = 1.f / fmaxf(sqrtf(G), 1e-12f);
  float* ob = out + (long)b * 8448;
  ob[tid] = tkv / tn * inv;
  for (int idx = tid; idx < 8192; idx += 256)
    ob[256 + idx] = asum[idx] / cn[idx & 63] * inv;
}

// ---------------------------------------------------------------------------
extern "C" void kernel_launch(void* const* d_in, const int* in_sizes, int n_in,
                              void* d_out, int out_size, void* d_ws,
                              size_t ws_size, hipStream_t stream) {
  const float* x = (const float*)d_in[0];
  const float* t = (const float*)d_in[1];
  const float* cf_w1 = (const float*)d_in[2];
  const float* cf_b1 = (const float*)d_in[3];
  const float* cf_w2 = (const float*)d_in[4];
  const float* cf_b2 = (const float*)d_in[5];
  const float* sc_w1 = (const float*)d_in[6];
  const float* sc_b1 = (const float*)d_in[7];
  const float* sc_w2 = (const float*)d_in[8];
  const float* sc_b2 = (const float*)d_in[9];
  const float* tk_w1 = (const float*)d_in[10];
  const float* tk_b1 = (const float*)d_in[11];
  const float* tk_w2 = (const float*)d_in[12];
  const float* tk_b2 = (const float*)d_in[13];
  const float* dust = (const float*)d_in[14];
  float* out = (float*)d_out;

  char* ws = (char*)d_ws;
  size_t off = 0;
  u16* wc1 = (u16*)(ws + off); off += (size_t)512 * 1536 * 2;
  u16* ws1 = (u16*)(ws + off); off += (size_t)512 * 1536 * 2;
  u16* wc2 = (u16*)(ws + off); off += (size_t)128 * 512 * 2;
  u16* ws2p = (u16*)(ws + off); off += (size_t)128 * 512 * 2;
  float* scb2p = (float*)(ws + off); off += (size_t)128 * 4;
  u16* f = (u16*)(ws + off);   off += (size_t)32 * 128 * 1024 * 2;
  u16* scr = (u16*)(ws + off); off += (size_t)32 * 128 * 1024 * 2;
  u16* P = (u16*)(ws + off);   off += (size_t)32 * 64 * 1024 * 2;
  float* aggP = (float*)(ws + off); off += (size_t)4 * 32 * 128 * 64 * 4;
  float* h1ws = (float*)(ws + off); off += (size_t)32 * 512 * 4;
  float* tkws = (float*)(ws + off); off += (size_t)32 * 256 * 4;
  size_t fixed = off;
  size_t perB = (size_t)1024 * 1536 * 2 + (size_t)1024 * 1024 * 2;
  int c = 1;
  const int cands[6] = {32, 16, 8, 4, 2, 1};
  for (int k = 0; k < 6; ++k)
    if (fixed + (size_t)cands[k] * perB <= ws_size) { c = cands[k]; break; }
  u16* xT = (u16*)(ws + fixed);
  u16* hT = (u16*)(ws + fixed + (size_t)c * 1024 * 1536 * 2);

  k_prep<<<dim3(768, 5), 256, 0, stream>>>(cf_w1, wc1, sc_w1, ws1, cf_w2, wc2,
                                           sc_w2, ws2p, sc_b2, scb2p);

  k_mlp1<<<dim3(8, 32), 256, 0, stream>>>(t, tk_w1, tk_b1, h1ws);
  k_mlp2<<<dim3(4, 32), 256, 0, stream>>>(h1ws, tk_w2, tk_b2, tkws);

  float norm = -logf(1088.f);
  float lmu = norm;
  float lmu_bin = logf(960.f) + norm;
  float lnu = norm;

  for (int cb = 0; cb < 32; cb += c) {
    k_transpose<<<dim3(16, 24, c), 256, 0, stream>>>(
        x + (size_t)cb * 1536 * 1024, xT, 1536, 1024);
    k_gemm64<24, false, 2, true><<<dim3(8, 8, c), 256, 0, stream>>>(
        xT, 1536, (long)1024 * 1536,
        wc1, ws1, 512, 1536, 0,
        hT, 1024, (long)1024 * 1024,
        cf_b1, sc_b1);
    k_k2dual<<<dim3(8, 2, c), 256, 0, stream>>>(
        wc2, ws2p, hT, f + (size_t)cb * 131072, scr + (size_t)cb * 131072,
        cf_b2, scb2p);
  }
  k_sinkhorn<<<32, 1024, 0, stream>>>(scr, dust, lmu, lmu_bin, lnu, norm, P);
  k_agg<<<dim3(4, 1, 32), 256, 0, stream>>>(f, P, aggP);
  k_norms<<<32, 256, 0, stream>>>(tkws, aggP, out);
}